// Round 6
// baseline (1411.979 us; speedup 1.0000x reference)
//
#include <hip/hip_runtime.h>
#include <hip/hip_bf16.h>
#include <cstdint>
#include <cstddef>

typedef __hip_bfloat16 bf16;
typedef __attribute__((ext_vector_type(8))) short bf16x8;
typedef __attribute__((ext_vector_type(4))) float floatx4;

static constexpr int Bb = 2;
static constexpr int Ls = 4096;
static constexpr int Dm = 1024;
static constexpr int Hn = 16;
static constexpr int HD = 64;
static constexpr int BS = 256;
static constexpr int QKVROW = 3 * Dm;  // 3072

static constexpr size_t NX  = (size_t)8192 * 1024;
static constexpr size_t NQ  = (size_t)8192 * 3072;
static constexpr size_t NW1 = (size_t)3072 * 1024;
static constexpr size_t NW2 = (size_t)1024 * 1024;

__device__ __forceinline__ void async_load16(const void* g, void* l) {
  __builtin_amdgcn_global_load_lds(
      (__attribute__((address_space(1))) void*)(void*)(g),
      (__attribute__((address_space(3))) void*)(l), 16, 0, 0);
}

__device__ __forceinline__ short f2bf(float f) {
  union { __hip_bfloat16 b; short s; } u;
  u.b = __float2bfloat16(f);
  return u.s;
}

__device__ __forceinline__ bf16x8 load8(const float* p) {
  const float4 f0 = *(const float4*)(const void*)p;
  const float4 f1 = *(const float4*)(const void*)(p + 4);
  bf16x8 r;
  r[0] = f2bf(f0.x); r[1] = f2bf(f0.y); r[2] = f2bf(f0.z); r[3] = f2bf(f0.w);
  r[4] = f2bf(f1.x); r[5] = f2bf(f1.y); r[6] = f2bf(f1.z); r[7] = f2bf(f1.w);
  return r;
}

__device__ __forceinline__ void storeC(bf16* C, size_t idx, float v) {
  C[idx] = __float2bfloat16(v);
}
__device__ __forceinline__ void storeC(float* C, size_t idx, float v) {
  C[idx] = v;
}

// Merged fp32->bf16 convert for x, Wqkv, Wout (regions 2048-aligned; block-uniform branch).
__global__ void cvt3_kernel(const float* __restrict__ x, const float* __restrict__ w1,
                            const float* __restrict__ w2, bf16* __restrict__ xb,
                            bf16* __restrict__ w1b, bf16* __restrict__ w2b) {
  const size_t i = ((size_t)blockIdx.x * 256 + threadIdx.x) * 8;
  if (i < NX) {
    *(bf16x8*)(void*)((short*)(void*)xb + i) = load8(x + i);
  } else if (i < NX + NW1) {
    const size_t k = i - NX;
    *(bf16x8*)(void*)((short*)(void*)w1b + k) = load8(w1 + k);
  } else {
    const size_t k = i - NX - NW1;
    *(bf16x8*)(void*)((short*)(void*)w2b + k) = load8(w2 + k);
  }
}

// All-bf16 GEMM, m97 structure (global_load_lds width=16), optional fused RoPE
// epilogue (applied when do_rope && tn<2048, i.e. q/k planes of the qkv output).
// C[m,n] = sum_k A[m,k]*B[n,k]; M%128==0, N%128==0, K%32==0.
template <typename TC>
__global__ __launch_bounds__(256) void gemm_bt_async(
    const bf16* __restrict__ A, const bf16* __restrict__ Bm, TC* __restrict__ C,
    int M, int N, int K, int do_rope) {
  __shared__ __align__(16) short sA[128 * 32];
  __shared__ __align__(16) short sB[128 * 32];
  const int tid  = threadIdx.x;
  const int wave = tid >> 6, lane = tid & 63;
  const int quad = lane >> 4, l15 = lane & 15;
  const int tm = blockIdx.y * 128, tn = blockIdx.x * 128;
  const int wm = (wave >> 1) * 64, wn = (wave & 1) * 64;

  floatx4 acc[4][4];
#pragma unroll
  for (int i = 0; i < 4; i++)
#pragma unroll
    for (int j = 0; j < 4; j++) acc[i][j] = {0.f, 0.f, 0.f, 0.f};

  const int srow = tid >> 2;          // 0..63
  const int scol = (tid & 3) * 8;     // 0,8,16,24
  const bf16* Ag0 = A + (size_t)(tm + srow) * K + scol;
  const bf16* Ag1 = A + (size_t)(tm + srow + 64) * K + scol;
  const bf16* Bg0 = Bm + (size_t)(tn + srow) * K + scol;
  const bf16* Bg1 = Bm + (size_t)(tn + srow + 64) * K + scol;
  short* sAd0 = sA + tid * 8;          // lane-contiguous (global_load_lds rule)
  short* sAd1 = sA + 2048 + tid * 8;
  short* sBd0 = sB + tid * 8;
  short* sBd1 = sB + 2048 + tid * 8;

  for (int kb = 0; kb < K; kb += 32) {
    __syncthreads();  // prior tile's ds_reads done before DMA overwrites
    async_load16(Ag0 + kb, sAd0);
    async_load16(Ag1 + kb, sAd1);
    async_load16(Bg0 + kb, sBd0);
    async_load16(Bg1 + kb, sBd1);
    __syncthreads();  // barrier drains vmcnt -> LDS tile valid

    bf16x8 af[4], bfr[4];
#pragma unroll
    for (int i = 0; i < 4; i++)
      af[i] = *(const bf16x8*)(sA + (wm + i * 16 + l15) * 32 + quad * 8);
#pragma unroll
    for (int j = 0; j < 4; j++)
      bfr[j] = *(const bf16x8*)(sB + (wn + j * 16 + l15) * 32 + quad * 8);
#pragma unroll
    for (int i = 0; i < 4; i++)
#pragma unroll
      for (int j = 0; j < 4; j++)
        acc[i][j] = __builtin_amdgcn_mfma_f32_16x16x32_bf16(af[i], bfr[j], acc[i][j], 0, 0, 0);
  }

  // Fused RoPE (q/k planes only). C/D layout: col=wn+j*16+l15, row=quad*4+r.
  // Output band pos i = jj*16+l15 (jj in {0,1}) takes inputs at band cols
  // 2i, 2i+1 = tile 2jj+(l15>>3), lanes quad*16+((2*l15)&15), +1 (same quad/row).
  // out[i] = A*c - B*s; out[i+32] = B*c + A*s; angle = l * 10000^(-2i/64).
  if (do_rope && tn < 2048) {
#pragma unroll
    for (int i = 0; i < 4; i++)
#pragma unroll
      for (int r = 0; r < 4; r++) {
        const int m = tm + wm + i * 16 + quad * 4 + r;
        const float t = (float)(m & (Ls - 1));
        float nacc[4];
#pragma unroll
        for (int jj = 0; jj < 2; jj++) {
          const int src = quad * 16 + ((2 * l15) & 15);
          const float a0 = __shfl(acc[i][2 * jj][r],     src,     64);
          const float a1 = __shfl(acc[i][2 * jj + 1][r], src,     64);
          const float b0 = __shfl(acc[i][2 * jj][r],     src + 1, 64);
          const float b1 = __shfl(acc[i][2 * jj + 1][r], src + 1, 64);
          const bool hi = (l15 >> 3) & 1;
          const float Av = hi ? a1 : a0;
          const float Bv = hi ? b1 : b0;
          const int d = jj * 16 + l15;
          const float freq = exp2f(-13.287712379549449f * (float)(2 * d) * (1.0f / 64.0f));
          const float ang = t * freq;
          const float c = cosf(ang), s = sinf(ang);
          nacc[jj]     = Av * c - Bv * s;
          nacc[jj + 2] = Bv * c + Av * s;
        }
#pragma unroll
        for (int j = 0; j < 4; j++) acc[i][j][r] = nacc[j];
      }
  }

#pragma unroll
  for (int i = 0; i < 4; i++)
#pragma unroll
    for (int j = 0; j < 4; j++)
#pragma unroll
      for (int r = 0; r < 4; r++) {
        const int row = tm + wm + i * 16 + quad * 4 + r;  // C/D: row=quad*4+r
        const int col = tn + wn + j * 16 + l15;           //      col=lane&15
        storeC(C, (size_t)row * N + col, acc[i][j][r]);
      }
}

// One block per (blk, h, b): 256x256 causal attention within the block.
// BALANCED: 8 q-strips of 32 rows; wave w owns strips {w, 7-w} -> every wave
// does exactly 5 strip-chunk iterations (strip s needs s/2+1 key-chunks of 64).
__global__ __launch_bounds__(256) void attn_kernel(const bf16* __restrict__ qkv,
                                                   bf16* __restrict__ aout) {
  constexpr float SCALE = 0.125f;  // 64^-0.5
  constexpr float LOG2E = 1.4426950408889634f;
  __shared__ __align__(16) short vT[HD * BS];     // 32 KB: vT[d][key]
  __shared__ __align__(16) short pS[4][32 * 64];  // 16 KB: per-wave P scratch (32 rows)
  const int blk = blockIdx.x, h = blockIdx.y, b = blockIdx.z;
  const int tid = threadIdx.x;
  const int wave = tid >> 6, lane = tid & 63;
  const int quad = lane >> 4, l15 = lane & 15;
  const size_t row0 = (size_t)(b * Ls + blk * BS);
  const bf16* qkvR = qkv + row0 * QKVROW;

  // stage V^T: thread tid handles key = tid
  {
    const bf16* vrow = qkvR + (size_t)tid * QKVROW + 2 * Dm + h * HD;
#pragma unroll
    for (int i = 0; i < 8; i++) {
      bf16x8 vv = *(const bf16x8*)(vrow + i * 8);
#pragma unroll
      for (int e = 0; e < 8; e++) vT[(i * 8 + e) * BS + tid] = vv[e];
    }
  }
  __syncthreads();  // vT ready; no block barrier past this point

  short* myP = &pS[wave][0];

  for (int sp = 0; sp < 2; sp++) {
    const int s = sp ? (7 - wave) : wave;  // strip index 0..7
    const int qrow0 = s * 32;
    const int kcmax = s >> 1;

    // q fragments for this strip: A-layout m=lane&15, k=quad*8+j
    bf16x8 qf[2][2];
#pragma unroll
    for (int mt = 0; mt < 2; mt++)
#pragma unroll
      for (int ks = 0; ks < 2; ks++)
        qf[mt][ks] = *(const bf16x8*)(qkvR + (size_t)(qrow0 + mt * 16 + l15) * QKVROW
                                      + h * HD + ks * 32 + quad * 8);

    float m_i[2][4], l_i[2][4];
    floatx4 o[2][4];
#pragma unroll
    for (int mt = 0; mt < 2; mt++)
#pragma unroll
      for (int r = 0; r < 4; r++) { m_i[mt][r] = -1e30f; l_i[mt][r] = 0.f; }
#pragma unroll
    for (int mt = 0; mt < 2; mt++)
#pragma unroll
      for (int nt = 0; nt < 4; nt++) o[mt][nt] = {0.f, 0.f, 0.f, 0.f};

    for (int kc = 0; kc <= kcmax; kc++) {
      floatx4 sc[2][4];
#pragma unroll
      for (int mt = 0; mt < 2; mt++)
#pragma unroll
        for (int nt = 0; nt < 4; nt++) sc[mt][nt] = {0.f, 0.f, 0.f, 0.f};

      bf16x8 kf[4][2];
#pragma unroll
      for (int nt = 0; nt < 4; nt++)
#pragma unroll
        for (int ks = 0; ks < 2; ks++)
          kf[nt][ks] = *(const bf16x8*)(qkvR + (size_t)(kc * 64 + nt * 16 + l15) * QKVROW
                                        + Dm + h * HD + ks * 32 + quad * 8);

#pragma unroll
      for (int mt = 0; mt < 2; mt++)
#pragma unroll
        for (int nt = 0; nt < 4; nt++) {
          sc[mt][nt] = __builtin_amdgcn_mfma_f32_16x16x32_bf16(qf[mt][0], kf[nt][0], sc[mt][nt], 0, 0, 0);
          sc[mt][nt] = __builtin_amdgcn_mfma_f32_16x16x32_bf16(qf[mt][1], kf[nt][1], sc[mt][nt], 0, 0, 0);
        }

      const bool diag = (kc == kcmax);
#pragma unroll
      for (int mt = 0; mt < 2; mt++)
#pragma unroll
        for (int r = 0; r < 4; r++) {
          const int rowg = qrow0 + mt * 16 + quad * 4 + r;
          float cmax = -1e30f;
#pragma unroll
          for (int nt = 0; nt < 4; nt++) {
            float sv = sc[mt][nt][r] * SCALE;
            if (diag && (kc * 64 + nt * 16 + l15 > rowg)) sv = -1e30f;
            sc[mt][nt][r] = sv;
            cmax = fmaxf(cmax, sv);
          }
#pragma unroll
          for (int off = 1; off < 16; off <<= 1)
            cmax = fmaxf(cmax, __shfl_xor(cmax, off, 64));  // 16 lanes share a row
          const float mold = m_i[mt][r];
          const float mnew = fmaxf(mold, cmax);
          const float alpha = exp2f((mold - mnew) * LOG2E);
          float rsum = 0.f;
#pragma unroll
          for (int nt = 0; nt < 4; nt++) {
            const float p = exp2f((sc[mt][nt][r] - mnew) * LOG2E);
            sc[mt][nt][r] = p;
            rsum += p;
          }
#pragma unroll
          for (int off = 1; off < 16; off <<= 1)
            rsum += __shfl_xor(rsum, off, 64);
          l_i[mt][r] = l_i[mt][r] * alpha + rsum;
          m_i[mt][r] = mnew;
#pragma unroll
          for (int nt = 0; nt < 4; nt++) o[mt][nt][r] *= alpha;
        }

      // V fragments for this key-chunk
      bf16x8 vf0[4], vf1[4];
#pragma unroll
      for (int nt = 0; nt < 4; nt++) {
        vf0[nt] = *(const bf16x8*)(vT + (nt * 16 + l15) * BS + kc * 64 + quad * 8);
        vf1[nt] = *(const bf16x8*)(vT + (nt * 16 + l15) * BS + kc * 64 + 32 + quad * 8);
      }

      // P: C-layout -> LDS -> A-layout (wave-private; per-wave DS ops in-order)
#pragma unroll
      for (int mt = 0; mt < 2; mt++)
#pragma unroll
        for (int nt = 0; nt < 4; nt++)
#pragma unroll
          for (int r = 0; r < 4; r++)
            myP[(mt * 16 + quad * 4 + r) * 64 + nt * 16 + l15] = f2bf(sc[mt][nt][r]);

      __asm__ __volatile__("s_waitcnt lgkmcnt(0)" ::: "memory");

#pragma unroll
      for (int mt = 0; mt < 2; mt++) {
        const bf16x8 pf0 = *(const bf16x8*)(myP + (mt * 16 + l15) * 64 + quad * 8);
        const bf16x8 pf1 = *(const bf16x8*)(myP + (mt * 16 + l15) * 64 + 32 + quad * 8);
#pragma unroll
        for (int nt = 0; nt < 4; nt++) {
          o[mt][nt] = __builtin_amdgcn_mfma_f32_16x16x32_bf16(pf0, vf0[nt], o[mt][nt], 0, 0, 0);
          o[mt][nt] = __builtin_amdgcn_mfma_f32_16x16x32_bf16(pf1, vf1[nt], o[mt][nt], 0, 0, 0);
        }
      }
      __asm__ __volatile__("s_waitcnt lgkmcnt(0)" ::: "memory");  // reads done before next pack
    }

    // normalize and store strip (B,L,H,HD) -> row-major (B*L, 1024)
#pragma unroll
    for (int mt = 0; mt < 2; mt++)
#pragma unroll
      for (int r = 0; r < 4; r++) {
        const float inv = 1.0f / l_i[mt][r];
#pragma unroll
        for (int nt = 0; nt < 4; nt++) {
          const size_t m = row0 + qrow0 + mt * 16 + quad * 4 + r;
          aout[m * Dm + h * HD + nt * 16 + l15] = __float2bfloat16(o[mt][nt][r] * inv);
        }
      }
  }
}

extern "C" void kernel_launch(void* const* d_in, const int* in_sizes, int n_in,
                              void* d_out, int out_size, void* d_ws, size_t ws_size,
                              hipStream_t stream) {
  const float* x    = (const float*)d_in[0];   // (2,4096,1024) fp32
  const float* Wqkv = (const float*)d_in[1];   // (3072,1024) fp32
  const float* Wout = (const float*)d_in[2];   // (1024,1024) fp32
  float* out = (float*)d_out;                  // (2,4096,1024) fp32

  bf16* xb    = (bf16*)d_ws;        // 16.8 MB; dead after QKV GEMM -> reused as attnb
  bf16* qkv   = xb + NX;            // 50.3 MB
  bf16* Wqkvb = qkv + NQ;           // 6.3 MB
  bf16* Woutb = Wqkvb + NW1;        // 2.1 MB
  bf16* attnb = xb;                 // alias (xb dead by then)

  cvt3_kernel<<<(NX + NW1 + NW2) / 2048, 256, 0, stream>>>(x, Wqkv, Wout, xb, Wqkvb, Woutb);

  // qkv = rope(x @ Wqkv^T) with RoPE fused into the epilogue for q/k planes
  gemm_bt_async<bf16>
      <<<dim3(3072 / 128, 8192 / 128), 256, 0, stream>>>(xb, Wqkvb, qkv, 8192, 3072, 1024, 1);
  attn_kernel<<<dim3(Ls / BS, Hn, Bb), 256, 0, stream>>>(qkv, attnb);
  gemm_bt_async<float>
      <<<dim3(1024 / 128, 8192 / 128), 256, 0, stream>>>(attnb, Woutb, out, 8192, 1024, 1024, 0);
}

// Round 7
// 538.101 us; speedup vs baseline: 2.6240x; 2.6240x over previous
//
#include <hip/hip_runtime.h>
#include <hip/hip_bf16.h>
#include <cstdint>
#include <cstddef>

typedef __hip_bfloat16 bf16;
typedef __attribute__((ext_vector_type(8))) short bf16x8;
typedef __attribute__((ext_vector_type(4))) float floatx4;

static constexpr int Bb = 2;
static constexpr int Ls = 4096;
static constexpr int Dm = 1024;
static constexpr int Hn = 16;
static constexpr int HD = 64;
static constexpr int BS = 256;
static constexpr int QKVROW = 3 * Dm;  // 3072

static constexpr size_t NX  = (size_t)8192 * 1024;
static constexpr size_t NQ  = (size_t)8192 * 3072;
static constexpr size_t NW1 = (size_t)3072 * 1024;
static constexpr size_t NW2 = (size_t)1024 * 1024;

__device__ __forceinline__ void async_load16(const void* g, void* l) {
  __builtin_amdgcn_global_load_lds(
      (__attribute__((address_space(1))) void*)(void*)(g),
      (__attribute__((address_space(3))) void*)(l), 16, 0, 0);
}

__device__ __forceinline__ short f2bf(float f) {
  union { __hip_bfloat16 b; short s; } u;
  u.b = __float2bfloat16(f);
  return u.s;
}

__device__ __forceinline__ float bf2f(short s) {
  union { unsigned u; float f; } v;
  v.u = ((unsigned)(unsigned short)s) << 16;
  return v.f;
}

__device__ __forceinline__ bf16x8 load8(const float* p) {
  const float4 f0 = *(const float4*)(const void*)p;
  const float4 f1 = *(const float4*)(const void*)(p + 4);
  bf16x8 r;
  r[0] = f2bf(f0.x); r[1] = f2bf(f0.y); r[2] = f2bf(f0.z); r[3] = f2bf(f0.w);
  r[4] = f2bf(f1.x); r[5] = f2bf(f1.y); r[6] = f2bf(f1.z); r[7] = f2bf(f1.w);
  return r;
}

__device__ __forceinline__ void storeC(bf16* C, size_t idx, float v) {
  C[idx] = __float2bfloat16(v);
}
__device__ __forceinline__ void storeC(float* C, size_t idx, float v) {
  C[idx] = v;
}

// Merged fp32->bf16 convert for x, Wqkv, Wout (regions 2048-aligned; block-uniform branch).
__global__ void cvt3_kernel(const float* __restrict__ x, const float* __restrict__ w1,
                            const float* __restrict__ w2, bf16* __restrict__ xb,
                            bf16* __restrict__ w1b, bf16* __restrict__ w2b) {
  const size_t i = ((size_t)blockIdx.x * 256 + threadIdx.x) * 8;
  if (i < NX) {
    *(bf16x8*)(void*)((short*)(void*)xb + i) = load8(x + i);
  } else if (i < NX + NW1) {
    const size_t k = i - NX;
    *(bf16x8*)(void*)((short*)(void*)w1b + k) = load8(w1 + k);
  } else {
    const size_t k = i - NX - NW1;
    *(bf16x8*)(void*)((short*)(void*)w2b + k) = load8(w2 + k);
  }
}

// All-bf16 GEMM, m97 structure (global_load_lds width=16). ROUND-5 PROVEN FORM —
// no epilogue branches, no cross-lane ops (round 6 showed a shuffle epilogue
// demotes the 64-VGPR accumulator to scratch: VGPR 72->40, 5 GB scratch traffic).
// C[m,n] = sum_k A[m,k]*B[n,k]; M%128==0, N%128==0, K%32==0.
template <typename TC>
__global__ __launch_bounds__(256) void gemm_bt_async(
    const bf16* __restrict__ A, const bf16* __restrict__ Bm, TC* __restrict__ C,
    int M, int N, int K) {
  __shared__ __align__(16) short sA[128 * 32];
  __shared__ __align__(16) short sB[128 * 32];
  const int tid  = threadIdx.x;
  const int wave = tid >> 6, lane = tid & 63;
  const int quad = lane >> 4, l15 = lane & 15;
  const int tm = blockIdx.y * 128, tn = blockIdx.x * 128;
  const int wm = (wave >> 1) * 64, wn = (wave & 1) * 64;

  floatx4 acc[4][4];
#pragma unroll
  for (int i = 0; i < 4; i++)
#pragma unroll
    for (int j = 0; j < 4; j++) acc[i][j] = {0.f, 0.f, 0.f, 0.f};

  const int srow = tid >> 2;          // 0..63
  const int scol = (tid & 3) * 8;     // 0,8,16,24
  const bf16* Ag0 = A + (size_t)(tm + srow) * K + scol;
  const bf16* Ag1 = A + (size_t)(tm + srow + 64) * K + scol;
  const bf16* Bg0 = Bm + (size_t)(tn + srow) * K + scol;
  const bf16* Bg1 = Bm + (size_t)(tn + srow + 64) * K + scol;
  short* sAd0 = sA + tid * 8;          // lane-contiguous (global_load_lds rule)
  short* sAd1 = sA + 2048 + tid * 8;
  short* sBd0 = sB + tid * 8;
  short* sBd1 = sB + 2048 + tid * 8;

  for (int kb = 0; kb < K; kb += 32) {
    __syncthreads();  // prior tile's ds_reads done before DMA overwrites
    async_load16(Ag0 + kb, sAd0);
    async_load16(Ag1 + kb, sAd1);
    async_load16(Bg0 + kb, sBd0);
    async_load16(Bg1 + kb, sBd1);
    __syncthreads();  // barrier drains vmcnt -> LDS tile valid

    bf16x8 af[4], bfr[4];
#pragma unroll
    for (int i = 0; i < 4; i++)
      af[i] = *(const bf16x8*)(sA + (wm + i * 16 + l15) * 32 + quad * 8);
#pragma unroll
    for (int j = 0; j < 4; j++)
      bfr[j] = *(const bf16x8*)(sB + (wn + j * 16 + l15) * 32 + quad * 8);
#pragma unroll
    for (int i = 0; i < 4; i++)
#pragma unroll
      for (int j = 0; j < 4; j++)
        acc[i][j] = __builtin_amdgcn_mfma_f32_16x16x32_bf16(af[i], bfr[j], acc[i][j], 0, 0, 0);
  }

#pragma unroll
  for (int i = 0; i < 4; i++)
#pragma unroll
    for (int j = 0; j < 4; j++)
#pragma unroll
      for (int r = 0; r < 4; r++) {
        const int row = tm + wm + i * 16 + quad * 4 + r;  // C/D: row=quad*4+r
        const int col = tn + wn + j * 16 + l15;           //      col=lane&15
        storeC(C, (size_t)row * N + col, acc[i][j][r]);
      }
}

// Load one q/k row's two A-operand fragments with NeoX RoPE applied on the fly.
// Fragment elem j covers k-dim d = ks*32 + quad*8 + j; d&31 = quad*8+j for both
// ks, so inputs are the 16 contiguous elems at row[quad*16 .. +15]:
//   x1 = row[2i], x2 = row[2i+1], i = quad*8+j
//   f0[j] = x1*c - x2*s  (dims 0..31), f1[j] = x2*c + x1*s (dims 32..63)
// Lane-local only — no shuffles, no LDS.
__device__ __forceinline__ void rope_frag(const bf16* __restrict__ row, int quad,
                                          float l_pos, const float* __restrict__ freq8,
                                          bf16x8* f0, bf16x8* f1) {
  const bf16x8 w0 = *(const bf16x8*)(const void*)(row + quad * 16);
  const bf16x8 w1 = *(const bf16x8*)(const void*)(row + quad * 16 + 8);
#pragma unroll
  for (int j = 0; j < 8; j++) {
    const short s1 = (j < 4) ? w0[2 * j] : w1[2 * (j - 4)];
    const short s2 = (j < 4) ? w0[2 * j + 1] : w1[2 * (j - 4) + 1];
    const float x1 = bf2f(s1), x2 = bf2f(s2);
    const float ang = l_pos * freq8[j];
    const float c = cosf(ang), s = sinf(ang);
    (*f0)[j] = f2bf(x1 * c - x2 * s);
    (*f1)[j] = f2bf(x2 * c + x1 * s);
  }
}

// One block per (blk, h, b): 256x256 causal attention within the block.
// BALANCED: 8 q-strips of 32 rows; wave w owns strips {w, 7-w} -> every wave
// does exactly 5 strip-chunk iterations. RoPE applied to q/k at fragment load.
__global__ __launch_bounds__(256) void attn_kernel(const bf16* __restrict__ qkv,
                                                   bf16* __restrict__ aout) {
  constexpr float SCALE = 0.125f;  // 64^-0.5
  constexpr float LOG2E = 1.4426950408889634f;
  __shared__ __align__(16) short vT[HD * BS];     // 32 KB: vT[d][key]
  __shared__ __align__(16) short pS[4][32 * 64];  // 16 KB: per-wave P scratch (32 rows)
  const int blk = blockIdx.x, h = blockIdx.y, b = blockIdx.z;
  const int tid = threadIdx.x;
  const int wave = tid >> 6, lane = tid & 63;
  const int quad = lane >> 4, l15 = lane & 15;
  const size_t row0 = (size_t)(b * Ls + blk * BS);
  const bf16* qkvR = qkv + row0 * QKVROW;

  // inv_freq for this lane's 8 fragment positions: i = quad*8+j
  float freq8[8];
#pragma unroll
  for (int j = 0; j < 8; j++)
    freq8[j] = exp2f(-13.287712379549449f * (float)(2 * (quad * 8 + j)) * (1.0f / 64.0f));

  // stage V^T: thread tid handles key = tid (V is NOT roped)
  {
    const bf16* vrow = qkvR + (size_t)tid * QKVROW + 2 * Dm + h * HD;
#pragma unroll
    for (int i = 0; i < 8; i++) {
      bf16x8 vv = *(const bf16x8*)(vrow + i * 8);
#pragma unroll
      for (int e = 0; e < 8; e++) vT[(i * 8 + e) * BS + tid] = vv[e];
    }
  }
  __syncthreads();  // vT ready; no block barrier past this point

  short* myP = &pS[wave][0];

  for (int sp = 0; sp < 2; sp++) {
    const int s = sp ? (7 - wave) : wave;  // strip index 0..7
    const int qrow0 = s * 32;
    const int kcmax = s >> 1;

    // roped q fragments for this strip: A-layout m=lane&15, k=quad*8+j
    bf16x8 qf[2][2];
#pragma unroll
    for (int mt = 0; mt < 2; mt++) {
      const int qr = qrow0 + mt * 16 + l15;
      rope_frag(qkvR + (size_t)qr * QKVROW + h * HD, quad,
                (float)(blk * BS + qr), freq8, &qf[mt][0], &qf[mt][1]);
    }

    float m_i[2][4], l_i[2][4];
    floatx4 o[2][4];
#pragma unroll
    for (int mt = 0; mt < 2; mt++)
#pragma unroll
      for (int r = 0; r < 4; r++) { m_i[mt][r] = -1e30f; l_i[mt][r] = 0.f; }
#pragma unroll
    for (int mt = 0; mt < 2; mt++)
#pragma unroll
      for (int nt = 0; nt < 4; nt++) o[mt][nt] = {0.f, 0.f, 0.f, 0.f};

    for (int kc = 0; kc <= kcmax; kc++) {
      floatx4 sc[2][4];
#pragma unroll
      for (int mt = 0; mt < 2; mt++)
#pragma unroll
        for (int nt = 0; nt < 4; nt++) sc[mt][nt] = {0.f, 0.f, 0.f, 0.f};

      // roped k fragments for this key-chunk
      bf16x8 kf[4][2];
#pragma unroll
      for (int nt = 0; nt < 4; nt++) {
        const int kr = kc * 64 + nt * 16 + l15;
        rope_frag(qkvR + (size_t)kr * QKVROW + Dm + h * HD, quad,
                  (float)(blk * BS + kr), freq8, &kf[nt][0], &kf[nt][1]);
      }

#pragma unroll
      for (int mt = 0; mt < 2; mt++)
#pragma unroll
        for (int nt = 0; nt < 4; nt++) {
          sc[mt][nt] = __builtin_amdgcn_mfma_f32_16x16x32_bf16(qf[mt][0], kf[nt][0], sc[mt][nt], 0, 0, 0);
          sc[mt][nt] = __builtin_amdgcn_mfma_f32_16x16x32_bf16(qf[mt][1], kf[nt][1], sc[mt][nt], 0, 0, 0);
        }

      const bool diag = (kc == kcmax);
#pragma unroll
      for (int mt = 0; mt < 2; mt++)
#pragma unroll
        for (int r = 0; r < 4; r++) {
          const int rowg = qrow0 + mt * 16 + quad * 4 + r;
          float cmax = -1e30f;
#pragma unroll
          for (int nt = 0; nt < 4; nt++) {
            float sv = sc[mt][nt][r] * SCALE;
            if (diag && (kc * 64 + nt * 16 + l15 > rowg)) sv = -1e30f;
            sc[mt][nt][r] = sv;
            cmax = fmaxf(cmax, sv);
          }
#pragma unroll
          for (int off = 1; off < 16; off <<= 1)
            cmax = fmaxf(cmax, __shfl_xor(cmax, off, 64));  // 16 lanes share a row
          const float mold = m_i[mt][r];
          const float mnew = fmaxf(mold, cmax);
          const float alpha = exp2f((mold - mnew) * LOG2E);
          float rsum = 0.f;
#pragma unroll
          for (int nt = 0; nt < 4; nt++) {
            const float p = exp2f((sc[mt][nt][r] - mnew) * LOG2E);
            sc[mt][nt][r] = p;
            rsum += p;
          }
#pragma unroll
          for (int off = 1; off < 16; off <<= 1)
            rsum += __shfl_xor(rsum, off, 64);
          l_i[mt][r] = l_i[mt][r] * alpha + rsum;
          m_i[mt][r] = mnew;
#pragma unroll
          for (int nt = 0; nt < 4; nt++) o[mt][nt][r] *= alpha;
        }

      // V fragments for this key-chunk
      bf16x8 vf0[4], vf1[4];
#pragma unroll
      for (int nt = 0; nt < 4; nt++) {
        vf0[nt] = *(const bf16x8*)(vT + (nt * 16 + l15) * BS + kc * 64 + quad * 8);
        vf1[nt] = *(const bf16x8*)(vT + (nt * 16 + l15) * BS + kc * 64 + 32 + quad * 8);
      }

      // P: C-layout -> LDS -> A-layout (wave-private; per-wave DS ops in-order)
#pragma unroll
      for (int mt = 0; mt < 2; mt++)
#pragma unroll
        for (int nt = 0; nt < 4; nt++)
#pragma unroll
          for (int r = 0; r < 4; r++)
            myP[(mt * 16 + quad * 4 + r) * 64 + nt * 16 + l15] = f2bf(sc[mt][nt][r]);

      __asm__ __volatile__("s_waitcnt lgkmcnt(0)" ::: "memory");

#pragma unroll
      for (int mt = 0; mt < 2; mt++) {
        const bf16x8 pf0 = *(const bf16x8*)(myP + (mt * 16 + l15) * 64 + quad * 8);
        const bf16x8 pf1 = *(const bf16x8*)(myP + (mt * 16 + l15) * 64 + 32 + quad * 8);
#pragma unroll
        for (int nt = 0; nt < 4; nt++) {
          o[mt][nt] = __builtin_amdgcn_mfma_f32_16x16x32_bf16(pf0, vf0[nt], o[mt][nt], 0, 0, 0);
          o[mt][nt] = __builtin_amdgcn_mfma_f32_16x16x32_bf16(pf1, vf1[nt], o[mt][nt], 0, 0, 0);
        }
      }
      __asm__ __volatile__("s_waitcnt lgkmcnt(0)" ::: "memory");  // reads done before next pack
    }

    // normalize and store strip (B,L,H,HD) -> row-major (B*L, 1024)
#pragma unroll
    for (int mt = 0; mt < 2; mt++)
#pragma unroll
      for (int r = 0; r < 4; r++) {
        const float inv = 1.0f / l_i[mt][r];
#pragma unroll
        for (int nt = 0; nt < 4; nt++) {
          const size_t m = row0 + qrow0 + mt * 16 + quad * 4 + r;
          aout[m * Dm + h * HD + nt * 16 + l15] = __float2bfloat16(o[mt][nt][r] * inv);
        }
      }
  }
}

extern "C" void kernel_launch(void* const* d_in, const int* in_sizes, int n_in,
                              void* d_out, int out_size, void* d_ws, size_t ws_size,
                              hipStream_t stream) {
  const float* x    = (const float*)d_in[0];   // (2,4096,1024) fp32
  const float* Wqkv = (const float*)d_in[1];   // (3072,1024) fp32
  const float* Wout = (const float*)d_in[2];   // (1024,1024) fp32
  float* out = (float*)d_out;                  // (2,4096,1024) fp32

  bf16* xb    = (bf16*)d_ws;        // 16.8 MB; dead after QKV GEMM -> reused as attnb
  bf16* qkv   = xb + NX;            // 50.3 MB
  bf16* Wqkvb = qkv + NQ;           // 6.3 MB
  bf16* Woutb = Wqkvb + NW1;        // 2.1 MB
  bf16* attnb = xb;                 // alias (xb dead by then)

  cvt3_kernel<<<(NX + NW1 + NW2) / 2048, 256, 0, stream>>>(x, Wqkv, Wout, xb, Wqkvb, Woutb);

  gemm_bt_async<bf16>
      <<<dim3(3072 / 128, 8192 / 128), 256, 0, stream>>>(xb, Wqkvb, qkv, 8192, 3072, 1024);
  attn_kernel<<<dim3(Ls / BS, Hn, Bb), 256, 0, stream>>>(qkv, attnb);
  gemm_bt_async<float>
      <<<dim3(1024 / 128, 8192 / 128), 256, 0, stream>>>(attnb, Woutb, out, 8192, 1024, 1024);
}

// Round 8
// 231.261 us; speedup vs baseline: 6.1056x; 2.3268x over previous
//
#include <hip/hip_runtime.h>
#include <hip/hip_bf16.h>
#include <cstdint>
#include <cstddef>

typedef __hip_bfloat16 bf16;
typedef __attribute__((ext_vector_type(8))) short bf16x8;
typedef __attribute__((ext_vector_type(4))) float floatx4;

static constexpr int Bb = 2;
static constexpr int Ls = 4096;
static constexpr int Dm = 1024;
static constexpr int Hn = 16;
static constexpr int HD = 64;
static constexpr int BS = 256;
static constexpr int QKVROW = 3 * Dm;  // 3072

static constexpr size_t NX  = (size_t)8192 * 1024;
static constexpr size_t NQ  = (size_t)8192 * 3072;
static constexpr size_t NW1 = (size_t)3072 * 1024;
static constexpr size_t NW2 = (size_t)1024 * 1024;

__device__ __forceinline__ void async_load16(const void* g, void* l) {
  __builtin_amdgcn_global_load_lds(
      (__attribute__((address_space(1))) void*)(void*)(g),
      (__attribute__((address_space(3))) void*)(l), 16, 0, 0);
}

__device__ __forceinline__ short f2bf(float f) {
  union { __hip_bfloat16 b; short s; } u;
  u.b = __float2bfloat16(f);
  return u.s;
}

__device__ __forceinline__ float bf2f(short s) {
  union { unsigned u; float f; } v;
  v.u = ((unsigned)(unsigned short)s) << 16;
  return v.f;
}

__device__ __forceinline__ bf16x8 load8(const float* p) {
  const float4 f0 = *(const float4*)(const void*)p;
  const float4 f1 = *(const float4*)(const void*)(p + 4);
  bf16x8 r;
  r[0] = f2bf(f0.x); r[1] = f2bf(f0.y); r[2] = f2bf(f0.z); r[3] = f2bf(f0.w);
  r[4] = f2bf(f1.x); r[5] = f2bf(f1.y); r[6] = f2bf(f1.z); r[7] = f2bf(f1.w);
  return r;
}

__device__ __forceinline__ void storeC(bf16* C, size_t idx, float v) {
  C[idx] = __float2bfloat16(v);
}
__device__ __forceinline__ void storeC(float* C, size_t idx, float v) {
  C[idx] = v;
}

// Merged fp32->bf16 convert for x, Wqkv, Wout (regions 2048-aligned; block-uniform branch).
__global__ void cvt3_kernel(const float* __restrict__ x, const float* __restrict__ w1,
                            const float* __restrict__ w2, bf16* __restrict__ xb,
                            bf16* __restrict__ w1b, bf16* __restrict__ w2b) {
  const size_t i = ((size_t)blockIdx.x * 256 + threadIdx.x) * 8;
  if (i < NX) {
    *(bf16x8*)(void*)((short*)(void*)xb + i) = load8(x + i);
  } else if (i < NX + NW1) {
    const size_t k = i - NX;
    *(bf16x8*)(void*)((short*)(void*)w1b + k) = load8(w1 + k);
  } else {
    const size_t k = i - NX - NW1;
    *(bf16x8*)(void*)((short*)(void*)w2b + k) = load8(w2 + k);
  }
}

// All-bf16 GEMM, m97 structure (global_load_lds width=16). ROUND-5 PROVEN FORM —
// no epilogue branches, no cross-lane ops (round 6: shuffle epilogue demoted the
// 64-VGPR accumulator to scratch -> 5 GB of spill traffic).
// C[m,n] = sum_k A[m,k]*B[n,k]; M%128==0, N%128==0, K%32==0.
template <typename TC>
__global__ __launch_bounds__(256) void gemm_bt_async(
    const bf16* __restrict__ A, const bf16* __restrict__ Bm, TC* __restrict__ C,
    int M, int N, int K) {
  __shared__ __align__(16) short sA[128 * 32];
  __shared__ __align__(16) short sB[128 * 32];
  const int tid  = threadIdx.x;
  const int wave = tid >> 6, lane = tid & 63;
  const int quad = lane >> 4, l15 = lane & 15;
  const int tm = blockIdx.y * 128, tn = blockIdx.x * 128;
  const int wm = (wave >> 1) * 64, wn = (wave & 1) * 64;

  floatx4 acc[4][4];
#pragma unroll
  for (int i = 0; i < 4; i++)
#pragma unroll
    for (int j = 0; j < 4; j++) acc[i][j] = {0.f, 0.f, 0.f, 0.f};

  const int srow = tid >> 2;          // 0..63
  const int scol = (tid & 3) * 8;     // 0,8,16,24
  const bf16* Ag0 = A + (size_t)(tm + srow) * K + scol;
  const bf16* Ag1 = A + (size_t)(tm + srow + 64) * K + scol;
  const bf16* Bg0 = Bm + (size_t)(tn + srow) * K + scol;
  const bf16* Bg1 = Bm + (size_t)(tn + srow + 64) * K + scol;
  short* sAd0 = sA + tid * 8;          // lane-contiguous (global_load_lds rule)
  short* sAd1 = sA + 2048 + tid * 8;
  short* sBd0 = sB + tid * 8;
  short* sBd1 = sB + 2048 + tid * 8;

  for (int kb = 0; kb < K; kb += 32) {
    __syncthreads();  // prior tile's ds_reads done before DMA overwrites
    async_load16(Ag0 + kb, sAd0);
    async_load16(Ag1 + kb, sAd1);
    async_load16(Bg0 + kb, sBd0);
    async_load16(Bg1 + kb, sBd1);
    __syncthreads();  // barrier drains vmcnt -> LDS tile valid

    bf16x8 af[4], bfr[4];
#pragma unroll
    for (int i = 0; i < 4; i++)
      af[i] = *(const bf16x8*)(sA + (wm + i * 16 + l15) * 32 + quad * 8);
#pragma unroll
    for (int j = 0; j < 4; j++)
      bfr[j] = *(const bf16x8*)(sB + (wn + j * 16 + l15) * 32 + quad * 8);
#pragma unroll
    for (int i = 0; i < 4; i++)
#pragma unroll
      for (int j = 0; j < 4; j++)
        acc[i][j] = __builtin_amdgcn_mfma_f32_16x16x32_bf16(af[i], bfr[j], acc[i][j], 0, 0, 0);
  }

#pragma unroll
  for (int i = 0; i < 4; i++)
#pragma unroll
    for (int j = 0; j < 4; j++)
#pragma unroll
      for (int r = 0; r < 4; r++) {
        const int row = tm + wm + i * 16 + quad * 4 + r;  // C/D: row=quad*4+r
        const int col = tn + wn + j * 16 + l15;           //      col=lane&15
        storeC(C, (size_t)row * N + col, acc[i][j][r]);
      }
}

// Load one q/k row's two A/B-operand fragments with NeoX RoPE applied on the fly.
// Fragment elem j covers k-dim d = ks*32 + quad*8 + j; d&31 = quad*8+j for both
// ks, so inputs are the 16 contiguous elems at row[quad*16 .. +15]:
//   x1 = row[2i], x2 = row[2i+1], i = quad*8+j
//   f0[j] = x1*c - x2*s  (dims 0..31), f1[j] = x2*c + x1*s (dims 32..63)
// HW transcendentals: v_sin/v_cos take REVOLUTIONS (D=sin(2pi*x)), reduce with
// fract first (cdna4_isa §3). freq8 is pre-divided by 2pi. Round 7 lesson:
// libm cosf/sinf here cost +320 us — never call __ocml in a hot loop.
__device__ __forceinline__ void rope_frag(const bf16* __restrict__ row, int quad,
                                          float l_pos, const float* __restrict__ freq8,
                                          bf16x8* f0, bf16x8* f1) {
  const bf16x8 w0 = *(const bf16x8*)(const void*)(row + quad * 16);
  const bf16x8 w1 = *(const bf16x8*)(const void*)(row + quad * 16 + 8);
#pragma unroll
  for (int j = 0; j < 8; j++) {
    const short s1 = (j < 4) ? w0[2 * j] : w1[2 * (j - 4)];
    const short s2 = (j < 4) ? w0[2 * j + 1] : w1[2 * (j - 4) + 1];
    const float x1 = bf2f(s1), x2 = bf2f(s2);
    const float rev = l_pos * freq8[j];        // angle in revolutions
    const float fr = rev - floorf(rev);        // reduce to [0,1)
    const float c = __builtin_amdgcn_cosf(fr); // v_cos_f32: cos(2pi*fr)
    const float s = __builtin_amdgcn_sinf(fr); // v_sin_f32: sin(2pi*fr)
    (*f0)[j] = f2bf(x1 * c - x2 * s);
    (*f1)[j] = f2bf(x2 * c + x1 * s);
  }
}

// One block per (blk, h, b): 256x256 causal attention within the block.
// BALANCED: 8 q-strips of 32 rows; wave w owns strips {w, 7-w} -> every wave
// does exactly 5 strip-chunk iterations. RoPE applied to q/k at fragment load.
__global__ __launch_bounds__(256) void attn_kernel(const bf16* __restrict__ qkv,
                                                   bf16* __restrict__ aout) {
  constexpr float SCALE = 0.125f;  // 64^-0.5
  constexpr float LOG2E = 1.4426950408889634f;
  constexpr float INV2PI = 0.15915494309189535f;
  __shared__ __align__(16) short vT[HD * BS];     // 32 KB: vT[d][key]
  __shared__ __align__(16) short pS[4][32 * 64];  // 16 KB: per-wave P scratch (32 rows)
  const int blk = blockIdx.x, h = blockIdx.y, b = blockIdx.z;
  const int tid = threadIdx.x;
  const int wave = tid >> 6, lane = tid & 63;
  const int quad = lane >> 4, l15 = lane & 15;
  const size_t row0 = (size_t)(b * Ls + blk * BS);
  const bf16* qkvR = qkv + row0 * QKVROW;

  // inv_freq (in revolutions) for this lane's 8 fragment positions: i = quad*8+j
  float freq8[8];
#pragma unroll
  for (int j = 0; j < 8; j++)
    freq8[j] = exp2f(-13.287712379549449f * (float)(2 * (quad * 8 + j)) * (1.0f / 64.0f))
               * INV2PI;

  // stage V^T: thread tid handles key = tid (V is NOT roped)
  {
    const bf16* vrow = qkvR + (size_t)tid * QKVROW + 2 * Dm + h * HD;
#pragma unroll
    for (int i = 0; i < 8; i++) {
      bf16x8 vv = *(const bf16x8*)(vrow + i * 8);
#pragma unroll
      for (int e = 0; e < 8; e++) vT[(i * 8 + e) * BS + tid] = vv[e];
    }
  }
  __syncthreads();  // vT ready; no block barrier past this point

  short* myP = &pS[wave][0];

  for (int sp = 0; sp < 2; sp++) {
    const int s = sp ? (7 - wave) : wave;  // strip index 0..7
    const int qrow0 = s * 32;
    const int kcmax = s >> 1;

    // roped q fragments for this strip: A-layout m=lane&15, k=quad*8+j
    bf16x8 qf[2][2];
#pragma unroll
    for (int mt = 0; mt < 2; mt++) {
      const int qr = qrow0 + mt * 16 + l15;
      rope_frag(qkvR + (size_t)qr * QKVROW + h * HD, quad,
                (float)(blk * BS + qr), freq8, &qf[mt][0], &qf[mt][1]);
    }

    float m_i[2][4], l_i[2][4];
    floatx4 o[2][4];
#pragma unroll
    for (int mt = 0; mt < 2; mt++)
#pragma unroll
      for (int r = 0; r < 4; r++) { m_i[mt][r] = -1e30f; l_i[mt][r] = 0.f; }
#pragma unroll
    for (int mt = 0; mt < 2; mt++)
#pragma unroll
      for (int nt = 0; nt < 4; nt++) o[mt][nt] = {0.f, 0.f, 0.f, 0.f};

    for (int kc = 0; kc <= kcmax; kc++) {
      floatx4 sc[2][4];
#pragma unroll
      for (int mt = 0; mt < 2; mt++)
#pragma unroll
        for (int nt = 0; nt < 4; nt++) sc[mt][nt] = {0.f, 0.f, 0.f, 0.f};

      // roped k fragments for this key-chunk
      bf16x8 kf[4][2];
#pragma unroll
      for (int nt = 0; nt < 4; nt++) {
        const int kr = kc * 64 + nt * 16 + l15;
        rope_frag(qkvR + (size_t)kr * QKVROW + Dm + h * HD, quad,
                  (float)(blk * BS + kr), freq8, &kf[nt][0], &kf[nt][1]);
      }

#pragma unroll
      for (int mt = 0; mt < 2; mt++)
#pragma unroll
        for (int nt = 0; nt < 4; nt++) {
          sc[mt][nt] = __builtin_amdgcn_mfma_f32_16x16x32_bf16(qf[mt][0], kf[nt][0], sc[mt][nt], 0, 0, 0);
          sc[mt][nt] = __builtin_amdgcn_mfma_f32_16x16x32_bf16(qf[mt][1], kf[nt][1], sc[mt][nt], 0, 0, 0);
        }

      const bool diag = (kc == kcmax);
#pragma unroll
      for (int mt = 0; mt < 2; mt++)
#pragma unroll
        for (int r = 0; r < 4; r++) {
          const int rowg = qrow0 + mt * 16 + quad * 4 + r;
          float cmax = -1e30f;
#pragma unroll
          for (int nt = 0; nt < 4; nt++) {
            float sv = sc[mt][nt][r] * SCALE;
            if (diag && (kc * 64 + nt * 16 + l15 > rowg)) sv = -1e30f;
            sc[mt][nt][r] = sv;
            cmax = fmaxf(cmax, sv);
          }
#pragma unroll
          for (int off = 1; off < 16; off <<= 1)
            cmax = fmaxf(cmax, __shfl_xor(cmax, off, 64));  // 16 lanes share a row
          const float mold = m_i[mt][r];
          const float mnew = fmaxf(mold, cmax);
          const float alpha = exp2f((mold - mnew) * LOG2E);
          float rsum = 0.f;
#pragma unroll
          for (int nt = 0; nt < 4; nt++) {
            const float p = exp2f((sc[mt][nt][r] - mnew) * LOG2E);
            sc[mt][nt][r] = p;
            rsum += p;
          }
#pragma unroll
          for (int off = 1; off < 16; off <<= 1)
            rsum += __shfl_xor(rsum, off, 64);
          l_i[mt][r] = l_i[mt][r] * alpha + rsum;
          m_i[mt][r] = mnew;
#pragma unroll
          for (int nt = 0; nt < 4; nt++) o[mt][nt][r] *= alpha;
        }

      // V fragments for this key-chunk
      bf16x8 vf0[4], vf1[4];
#pragma unroll
      for (int nt = 0; nt < 4; nt++) {
        vf0[nt] = *(const bf16x8*)(vT + (nt * 16 + l15) * BS + kc * 64 + quad * 8);
        vf1[nt] = *(const bf16x8*)(vT + (nt * 16 + l15) * BS + kc * 64 + 32 + quad * 8);
      }

      // P: C-layout -> LDS -> A-layout (wave-private; per-wave DS ops in-order)
#pragma unroll
      for (int mt = 0; mt < 2; mt++)
#pragma unroll
        for (int nt = 0; nt < 4; nt++)
#pragma unroll
          for (int r = 0; r < 4; r++)
            myP[(mt * 16 + quad * 4 + r) * 64 + nt * 16 + l15] = f2bf(sc[mt][nt][r]);

      __asm__ __volatile__("s_waitcnt lgkmcnt(0)" ::: "memory");

#pragma unroll
      for (int mt = 0; mt < 2; mt++) {
        const bf16x8 pf0 = *(const bf16x8*)(myP + (mt * 16 + l15) * 64 + quad * 8);
        const bf16x8 pf1 = *(const bf16x8*)(myP + (mt * 16 + l15) * 64 + 32 + quad * 8);
#pragma unroll
        for (int nt = 0; nt < 4; nt++) {
          o[mt][nt] = __builtin_amdgcn_mfma_f32_16x16x32_bf16(pf0, vf0[nt], o[mt][nt], 0, 0, 0);
          o[mt][nt] = __builtin_amdgcn_mfma_f32_16x16x32_bf16(pf1, vf1[nt], o[mt][nt], 0, 0, 0);
        }
      }
      __asm__ __volatile__("s_waitcnt lgkmcnt(0)" ::: "memory");  // reads done before next pack
    }

    // normalize and store strip (B,L,H,HD) -> row-major (B*L, 1024)
#pragma unroll
    for (int mt = 0; mt < 2; mt++)
#pragma unroll
      for (int r = 0; r < 4; r++) {
        const float inv = 1.0f / l_i[mt][r];
#pragma unroll
        for (int nt = 0; nt < 4; nt++) {
          const size_t m = row0 + qrow0 + mt * 16 + quad * 4 + r;
          aout[m * Dm + h * HD + nt * 16 + l15] = __float2bfloat16(o[mt][nt][r] * inv);
        }
      }
  }
}

extern "C" void kernel_launch(void* const* d_in, const int* in_sizes, int n_in,
                              void* d_out, int out_size, void* d_ws, size_t ws_size,
                              hipStream_t stream) {
  const float* x    = (const float*)d_in[0];   // (2,4096,1024) fp32
  const float* Wqkv = (const float*)d_in[1];   // (3072,1024) fp32
  const float* Wout = (const float*)d_in[2];   // (1024,1024) fp32
  float* out = (float*)d_out;                  // (2,4096,1024) fp32

  bf16* xb    = (bf16*)d_ws;        // 16.8 MB; dead after QKV GEMM -> reused as attnb
  bf16* qkv   = xb + NX;            // 50.3 MB
  bf16* Wqkvb = qkv + NQ;           // 6.3 MB
  bf16* Woutb = Wqkvb + NW1;        // 2.1 MB
  bf16* attnb = xb;                 // alias (xb dead by then)

  cvt3_kernel<<<(NX + NW1 + NW2) / 2048, 256, 0, stream>>>(x, Wqkv, Wout, xb, Wqkvb, Woutb);

  gemm_bt_async<bf16>
      <<<dim3(3072 / 128, 8192 / 128), 256, 0, stream>>>(xb, Wqkvb, qkv, 8192, 3072, 1024);
  attn_kernel<<<dim3(Ls / BS, Hn, Bb), 256, 0, stream>>>(qkv, attnb);
  gemm_bt_async<float>
      <<<dim3(1024 / 128, 8192 / 128), 256, 0, stream>>>(attnb, Woutb, out, 8192, 1024, 1024);
}

// Round 10
// 231.038 us; speedup vs baseline: 6.1115x; 1.0010x over previous
//
#include <hip/hip_runtime.h>
#include <hip/hip_bf16.h>
#include <cstdint>
#include <cstddef>

typedef __hip_bfloat16 bf16;
typedef __attribute__((ext_vector_type(8))) short bf16x8;
typedef __attribute__((ext_vector_type(4))) float floatx4;

static constexpr int Bb = 2;
static constexpr int Ls = 4096;
static constexpr int Dm = 1024;
static constexpr int Hn = 16;
static constexpr int HD = 64;
static constexpr int BS = 256;
static constexpr int QKVROW = 3 * Dm;  // 3072
static constexpr int KRP = 72;         // padded roped-K row stride (16B-aligned, breaks bank stride)

static constexpr size_t NX  = (size_t)8192 * 1024;
static constexpr size_t NQ  = (size_t)8192 * 3072;
static constexpr size_t NW1 = (size_t)3072 * 1024;
static constexpr size_t NW2 = (size_t)1024 * 1024;

__device__ __forceinline__ void async_load16(const void* g, void* l) {
  __builtin_amdgcn_global_load_lds(
      (__attribute__((address_space(1))) void*)(void*)(g),
      (__attribute__((address_space(3))) void*)(l), 16, 0, 0);
}

__device__ __forceinline__ short f2bf(float f) {
  union { __hip_bfloat16 b; short s; } u;
  u.b = __float2bfloat16(f);
  return u.s;
}

__device__ __forceinline__ float bf2f(short s) {
  union { unsigned u; float f; } v;
  v.u = ((unsigned)(unsigned short)s) << 16;
  return v.f;
}

__device__ __forceinline__ bf16x8 load8(const float* p) {
  const float4 f0 = *(const float4*)(const void*)p;
  const float4 f1 = *(const float4*)(const void*)(p + 4);
  bf16x8 r;
  r[0] = f2bf(f0.x); r[1] = f2bf(f0.y); r[2] = f2bf(f0.z); r[3] = f2bf(f0.w);
  r[4] = f2bf(f1.x); r[5] = f2bf(f1.y); r[6] = f2bf(f1.z); r[7] = f2bf(f1.w);
  return r;
}

__device__ __forceinline__ void storeC(bf16* C, size_t idx, float v) {
  C[idx] = __float2bfloat16(v);
}
__device__ __forceinline__ void storeC(float* C, size_t idx, float v) {
  C[idx] = v;
}

// Merged fp32->bf16 convert for x, Wqkv, Wout (regions 2048-aligned; block-uniform branch).
__global__ void cvt3_kernel(const float* __restrict__ x, const float* __restrict__ w1,
                            const float* __restrict__ w2, bf16* __restrict__ xb,
                            bf16* __restrict__ w1b, bf16* __restrict__ w2b) {
  const size_t i = ((size_t)blockIdx.x * 256 + threadIdx.x) * 8;
  if (i < NX) {
    *(bf16x8*)(void*)((short*)(void*)xb + i) = load8(x + i);
  } else if (i < NX + NW1) {
    const size_t k = i - NX;
    *(bf16x8*)(void*)((short*)(void*)w1b + k) = load8(w1 + k);
  } else {
    const size_t k = i - NX - NW1;
    *(bf16x8*)(void*)((short*)(void*)w2b + k) = load8(w2 + k);
  }
}

// All-bf16 GEMM, m97 structure (global_load_lds width=16). ROUND-5 PROVEN FORM —
// no epilogue branches, no cross-lane ops (round 6: shuffle epilogue demoted the
// 64-VGPR accumulator to scratch -> 5 GB of spill traffic).
// C[m,n] = sum_k A[m,k]*B[n,k]; M%128==0, N%128==0, K%32==0.
template <typename TC>
__global__ __launch_bounds__(256) void gemm_bt_async(
    const bf16* __restrict__ A, const bf16* __restrict__ Bm, TC* __restrict__ C,
    int M, int N, int K) {
  __shared__ __align__(16) short sA[128 * 32];
  __shared__ __align__(16) short sB[128 * 32];
  const int tid  = threadIdx.x;
  const int wave = tid >> 6, lane = tid & 63;
  const int quad = lane >> 4, l15 = lane & 15;
  const int tm = blockIdx.y * 128, tn = blockIdx.x * 128;
  const int wm = (wave >> 1) * 64, wn = (wave & 1) * 64;

  floatx4 acc[4][4];
#pragma unroll
  for (int i = 0; i < 4; i++)
#pragma unroll
    for (int j = 0; j < 4; j++) acc[i][j] = {0.f, 0.f, 0.f, 0.f};

  const int srow = tid >> 2;          // 0..63
  const int scol = (tid & 3) * 8;     // 0,8,16,24
  const bf16* Ag0 = A + (size_t)(tm + srow) * K + scol;
  const bf16* Ag1 = A + (size_t)(tm + srow + 64) * K + scol;
  const bf16* Bg0 = Bm + (size_t)(tn + srow) * K + scol;
  const bf16* Bg1 = Bm + (size_t)(tn + srow + 64) * K + scol;
  short* sAd0 = sA + tid * 8;          // lane-contiguous (global_load_lds rule)
  short* sAd1 = sA + 2048 + tid * 8;
  short* sBd0 = sB + tid * 8;
  short* sBd1 = sB + 2048 + tid * 8;

  for (int kb = 0; kb < K; kb += 32) {
    __syncthreads();  // prior tile's ds_reads done before DMA overwrites
    async_load16(Ag0 + kb, sAd0);
    async_load16(Ag1 + kb, sAd1);
    async_load16(Bg0 + kb, sBd0);
    async_load16(Bg1 + kb, sBd1);
    __syncthreads();  // barrier drains vmcnt -> LDS tile valid

    bf16x8 af[4], bfr[4];
#pragma unroll
    for (int i = 0; i < 4; i++)
      af[i] = *(const bf16x8*)(sA + (wm + i * 16 + l15) * 32 + quad * 8);
#pragma unroll
    for (int j = 0; j < 4; j++)
      bfr[j] = *(const bf16x8*)(sB + (wn + j * 16 + l15) * 32 + quad * 8);
#pragma unroll
    for (int i = 0; i < 4; i++)
#pragma unroll
      for (int j = 0; j < 4; j++)
        acc[i][j] = __builtin_amdgcn_mfma_f32_16x16x32_bf16(af[i], bfr[j], acc[i][j], 0, 0, 0);
  }

#pragma unroll
  for (int i = 0; i < 4; i++)
#pragma unroll
    for (int j = 0; j < 4; j++)
#pragma unroll
      for (int r = 0; r < 4; r++) {
        const int row = tm + wm + i * 16 + quad * 4 + r;  // C/D: row=quad*4+r
        const int col = tn + wn + j * 16 + l15;           //      col=lane&15
        storeC(C, (size_t)row * N + col, acc[i][j][r]);
      }
}

// Load one q row's two A-operand fragments with NeoX RoPE applied on the fly.
// Fragment elem j covers k-dim d = ks*32 + quad*8 + j; inputs at row[2i],row[2i+1],
// i = quad*8+j. HW transcendentals: v_sin/v_cos take REVOLUTIONS; reduce with
// fract first. freq8 pre-divided by 2pi. (Round 7: libm sincos here = +320 us.)
__device__ __forceinline__ void rope_frag(const bf16* __restrict__ row, int quad,
                                          float l_pos, const float* __restrict__ freq8,
                                          bf16x8* f0, bf16x8* f1) {
  const bf16x8 w0 = *(const bf16x8*)(const void*)(row + quad * 16);
  const bf16x8 w1 = *(const bf16x8*)(const void*)(row + quad * 16 + 8);
#pragma unroll
  for (int j = 0; j < 8; j++) {
    const short s1 = (j < 4) ? w0[2 * j] : w1[2 * (j - 4)];
    const short s2 = (j < 4) ? w0[2 * j + 1] : w1[2 * (j - 4) + 1];
    const float x1 = bf2f(s1), x2 = bf2f(s2);
    const float rev = l_pos * freq8[j];
    const float fr = rev - floorf(rev);
    const float c = __builtin_amdgcn_cosf(fr);
    const float s = __builtin_amdgcn_sinf(fr);
    (*f0)[j] = f2bf(x1 * c - x2 * s);
    (*f1)[j] = f2bf(x2 * c + x1 * s);
  }
}

// One block per (blk, h, b): 256x256 causal attention within the block.
// Roped K staged in LDS ONCE per block. kR stride 72 keeps 16B alignment and
// makes the 16-lane fragment read stride 36 dwords (2-way alias = free, m136).
// LDS: vT 32K + kR 36K + pS 8K = 76 KB -> 2 blocks/CU; grid 512 = 256 CU x 2
// exactly co-resident. (Round 9 bug: kw[4] loaded only half the 64-elem K row
// -> OOB reads of kw in the rope loop -> garbage upper-half K. Fixed: kw[8].)
__global__ __launch_bounds__(256) void attn_kernel(const bf16* __restrict__ qkv,
                                                   bf16* __restrict__ aout) {
  constexpr float SCALE = 0.125f;  // 64^-0.5
  constexpr float LOG2E = 1.4426950408889634f;
  constexpr float INV2PI = 0.15915494309189535f;
  __shared__ __align__(16) short vT[HD * BS];      // 32 KB: vT[d][key]
  __shared__ __align__(16) short kR[BS * KRP];     // 36 KB: roped K rows (padded)
  __shared__ __align__(16) short pS[4][16 * 64];   // 8 KB: per-wave P scratch (16 rows)
  const int blk = blockIdx.x, h = blockIdx.y, b = blockIdx.z;
  const int tid = threadIdx.x;
  const int wave = tid >> 6, lane = tid & 63;
  const int quad = lane >> 4, l15 = lane & 15;
  const size_t row0 = (size_t)(b * Ls + blk * BS);
  const bf16* qkvR = qkv + row0 * QKVROW;

  // inv_freq (revolutions) for this lane's q-fragment positions: i = quad*8+j
  float freq8[8];
#pragma unroll
  for (int j = 0; j < 8; j++)
    freq8[j] = exp2f(-13.287712379549449f * (float)(2 * (quad * 8 + j)) * (1.0f / 64.0f))
               * INV2PI;

  // stage V^T: thread tid handles key = tid (V is NOT roped)
  {
    const bf16* vrow = qkvR + (size_t)tid * QKVROW + 2 * Dm + h * HD;
#pragma unroll
    for (int i = 0; i < 8; i++) {
      bf16x8 vv = *(const bf16x8*)(vrow + i * 8);
#pragma unroll
      for (int e = 0; e < 8; e++) vT[(i * 8 + e) * BS + tid] = vv[e];
    }
  }

  // stage roped K: thread tid ropes the FULL 64-elem key-row tid (once/block)
  {
    const bf16* krow = qkvR + (size_t)tid * QKVROW + Dm + h * HD;
    bf16x8 kw[8];
#pragma unroll
    for (int t = 0; t < 8; t++) kw[t] = *(const bf16x8*)(krow + t * 8);
    const float pos = (float)(blk * BS + tid);
    short tmp[64];
#pragma unroll
    for (int i = 0; i < 32; i++) {
      const float x1 = bf2f(kw[(2 * i) >> 3][(2 * i) & 7]);
      const float x2 = bf2f(kw[(2 * i + 1) >> 3][(2 * i + 1) & 7]);
      const float fq = exp2f(-13.287712379549449f * (float)(2 * i) * (1.0f / 64.0f)) * INV2PI;
      const float rev = pos * fq;
      const float fr = rev - floorf(rev);
      const float c = __builtin_amdgcn_cosf(fr);
      const float s = __builtin_amdgcn_sinf(fr);
      tmp[i]      = f2bf(x1 * c - x2 * s);
      tmp[i + 32] = f2bf(x2 * c + x1 * s);
    }
#pragma unroll
    for (int t = 0; t < 8; t++)
      *(bf16x8*)(kR + tid * KRP + t * 8) = *(const bf16x8*)(tmp + t * 8);
  }
  __syncthreads();  // vT + kR ready; no block barrier past this point

  short* myP = &pS[wave][0];

  for (int sp = 0; sp < 2; sp++) {
    const int s = sp ? (7 - wave) : wave;  // strip index 0..7
    const int qrow0 = s * 32;
    const int kcmax = s >> 1;

    // roped q fragments for this strip: A-layout m=lane&15, k=quad*8+j
    bf16x8 qf[2][2];
#pragma unroll
    for (int mt = 0; mt < 2; mt++) {
      const int qr = qrow0 + mt * 16 + l15;
      rope_frag(qkvR + (size_t)qr * QKVROW + h * HD, quad,
                (float)(blk * BS + qr), freq8, &qf[mt][0], &qf[mt][1]);
    }

    float m_i[2][4], l_i[2][4];
    floatx4 o[2][4];
#pragma unroll
    for (int mt = 0; mt < 2; mt++)
#pragma unroll
      for (int r = 0; r < 4; r++) { m_i[mt][r] = -1e30f; l_i[mt][r] = 0.f; }
#pragma unroll
    for (int mt = 0; mt < 2; mt++)
#pragma unroll
      for (int nt = 0; nt < 4; nt++) o[mt][nt] = {0.f, 0.f, 0.f, 0.f};

    for (int kc = 0; kc <= kcmax; kc++) {
      floatx4 sc[2][4];
#pragma unroll
      for (int mt = 0; mt < 2; mt++)
#pragma unroll
        for (int nt = 0; nt < 4; nt++) sc[mt][nt] = {0.f, 0.f, 0.f, 0.f};

      // roped k fragments from LDS: B-row = kc*64+nt*16+l15, elem ks*32+quad*8+j
      bf16x8 kf[4][2];
#pragma unroll
      for (int nt = 0; nt < 4; nt++) {
        const short* kr = kR + (kc * 64 + nt * 16 + l15) * KRP;
        kf[nt][0] = *(const bf16x8*)(kr + quad * 8);
        kf[nt][1] = *(const bf16x8*)(kr + 32 + quad * 8);
      }

#pragma unroll
      for (int mt = 0; mt < 2; mt++)
#pragma unroll
        for (int nt = 0; nt < 4; nt++) {
          sc[mt][nt] = __builtin_amdgcn_mfma_f32_16x16x32_bf16(qf[mt][0], kf[nt][0], sc[mt][nt], 0, 0, 0);
          sc[mt][nt] = __builtin_amdgcn_mfma_f32_16x16x32_bf16(qf[mt][1], kf[nt][1], sc[mt][nt], 0, 0, 0);
        }

      const bool diag = (kc == kcmax);
#pragma unroll
      for (int mt = 0; mt < 2; mt++)
#pragma unroll
        for (int r = 0; r < 4; r++) {
          const int rowg = qrow0 + mt * 16 + quad * 4 + r;
          float cmax = -1e30f;
#pragma unroll
          for (int nt = 0; nt < 4; nt++) {
            float sv = sc[mt][nt][r] * SCALE;
            if (diag && (kc * 64 + nt * 16 + l15 > rowg)) sv = -1e30f;
            sc[mt][nt][r] = sv;
            cmax = fmaxf(cmax, sv);
          }
#pragma unroll
          for (int off = 1; off < 16; off <<= 1)
            cmax = fmaxf(cmax, __shfl_xor(cmax, off, 64));  // 16 lanes share a row
          const float mold = m_i[mt][r];
          const float mnew = fmaxf(mold, cmax);
          const float alpha = exp2f((mold - mnew) * LOG2E);
          float rsum = 0.f;
#pragma unroll
          for (int nt = 0; nt < 4; nt++) {
            const float p = exp2f((sc[mt][nt][r] - mnew) * LOG2E);
            sc[mt][nt][r] = p;
            rsum += p;
          }
#pragma unroll
          for (int off = 1; off < 16; off <<= 1)
            rsum += __shfl_xor(rsum, off, 64);
          l_i[mt][r] = l_i[mt][r] * alpha + rsum;
          m_i[mt][r] = mnew;
#pragma unroll
          for (int nt = 0; nt < 4; nt++) o[mt][nt][r] *= alpha;
        }

      // V fragments for this key-chunk
      bf16x8 vf0[4], vf1[4];
#pragma unroll
      for (int nt = 0; nt < 4; nt++) {
        vf0[nt] = *(const bf16x8*)(vT + (nt * 16 + l15) * BS + kc * 64 + quad * 8);
        vf1[nt] = *(const bf16x8*)(vT + (nt * 16 + l15) * BS + kc * 64 + 32 + quad * 8);
      }

      // P: C-layout -> LDS -> A-layout, one 16-row mt-half at a time
      // (wave-private buffer; per-wave DS ops are in-order)
#pragma unroll
      for (int mt = 0; mt < 2; mt++) {
#pragma unroll
        for (int nt = 0; nt < 4; nt++)
#pragma unroll
          for (int r = 0; r < 4; r++)
            myP[(quad * 4 + r) * 64 + nt * 16 + l15] = f2bf(sc[mt][nt][r]);
        __asm__ __volatile__("s_waitcnt lgkmcnt(0)" ::: "memory");
        const bf16x8 pf0 = *(const bf16x8*)(myP + l15 * 64 + quad * 8);
        const bf16x8 pf1 = *(const bf16x8*)(myP + l15 * 64 + 32 + quad * 8);
#pragma unroll
        for (int nt = 0; nt < 4; nt++) {
          o[mt][nt] = __builtin_amdgcn_mfma_f32_16x16x32_bf16(pf0, vf0[nt], o[mt][nt], 0, 0, 0);
          o[mt][nt] = __builtin_amdgcn_mfma_f32_16x16x32_bf16(pf1, vf1[nt], o[mt][nt], 0, 0, 0);
        }
        __asm__ __volatile__("s_waitcnt lgkmcnt(0)" ::: "memory");  // reads done before overwrite
      }
    }

    // normalize and store strip (B,L,H,HD) -> row-major (B*L, 1024)
#pragma unroll
    for (int mt = 0; mt < 2; mt++)
#pragma unroll
      for (int r = 0; r < 4; r++) {
        const float inv = 1.0f / l_i[mt][r];
#pragma unroll
        for (int nt = 0; nt < 4; nt++) {
          const size_t m = row0 + qrow0 + mt * 16 + quad * 4 + r;
          aout[m * Dm + h * HD + nt * 16 + l15] = __float2bfloat16(o[mt][nt][r] * inv);
        }
      }
  }
}

extern "C" void kernel_launch(void* const* d_in, const int* in_sizes, int n_in,
                              void* d_out, int out_size, void* d_ws, size_t ws_size,
                              hipStream_t stream) {
  const float* x    = (const float*)d_in[0];   // (2,4096,1024) fp32
  const float* Wqkv = (const float*)d_in[1];   // (3072,1024) fp32
  const float* Wout = (const float*)d_in[2];   // (1024,1024) fp32
  float* out = (float*)d_out;                  // (2,4096,1024) fp32

  bf16* xb    = (bf16*)d_ws;        // 16.8 MB; dead after QKV GEMM -> reused as attnb
  bf16* qkv   = xb + NX;            // 50.3 MB
  bf16* Wqkvb = qkv + NQ;           // 6.3 MB
  bf16* Woutb = Wqkvb + NW1;        // 2.1 MB
  bf16* attnb = xb;                 // alias (xb dead by then)

  cvt3_kernel<<<(NX + NW1 + NW2) / 2048, 256, 0, stream>>>(x, Wqkv, Wout, xb, Wqkvb, Woutb);

  gemm_bt_async<bf16>
      <<<dim3(3072 / 128, 8192 / 128), 256, 0, stream>>>(xb, Wqkvb, qkv, 8192, 3072, 1024);
  attn_kernel<<<dim3(Ls / BS, Hn, Bb), 256, 0, stream>>>(qkv, attnb);
  gemm_bt_async<float>
      <<<dim3(1024 / 128, 8192 / 128), 256, 0, stream>>>(attnb, Woutb, out, 8192, 1024, 1024);
}